// Round 2
// baseline (490.649 us; speedup 1.0000x reference)
//
#include <hip/hip_runtime.h>
#include <math.h>

#define NMAT 8192
#define GT   128                    // NMAT / 64 tiles per dim
#define NPAIRS (GT * (GT + 1) / 2)  // 8256
#define SP   16                     // tiles per super-tile edge
#define NST  (GT / SP)              // 8 super-tiles per dim

typedef float f4 __attribute__((ext_vector_type(4)));

// Module-scope scratch (d_ws proved too small in an earlier session).
// g_part[c][i] = contribution of column-tile c to rowsum[i]. Each slot is
// written by exactly ONE block (row-side writes c=bj>=bi, col-side writes
// c=bi<bj), so no init and no atomics are needed.
__device__ __align__(16) float g_part[GT][NMAT];   // 4 MiB
__device__ __align__(16) float g_dvec[NMAT];

// ---------------------------------------------------------------------------
// Super-tiled triangular pair decode: linear p -> (bi, bj), bi <= bj.
//
// DRAM-locality schedule: pairs are enumerated super-pair-major, where a
// super-pair is a 16x16 group of tile pairs (1024x1024 elements per panel
// block, 4 MB). 256 consecutive blockIdx values cover ONE mirror-pair
// region, so within the ~2000-block concurrency window each touched DRAM
// row gets 4 KB of near-simultaneous demand instead of 256 B scattered
// across the whole dispatch (the previous bi-major order streamed the
// transposed tiles as 256 B-per-32KB-row touches spread over all 8192
// rows -> HBM row-activation bound at ~1.7 TB/s).
//
// Enumeration: super-pair rows BI-major; diagonal super-pair holds 136
// triangular tile pairs, off-diagonal 256. Totals: 8*136 + 28*256 = 8256.
__device__ __forceinline__ void decode_pair_sp(int p, int& bi, int& bj) {
    int BI = 0;
    int rem = p;
    for (;;) {
        int rowcnt = 136 + 256 * (NST - 1 - BI);
        if (rem < rowcnt) break;
        rem -= rowcnt;
        ++BI;
    }
    int BJ, ti, tj;
    if (rem < 136) {
        BJ = BI;
        int t = 0;
        while (rem >= (SP - t)) { rem -= (SP - t); ++t; }
        ti = t;
        tj = t + rem;
    } else {
        rem -= 136;
        BJ = BI + 1 + (rem >> 8);
        int q = rem & 255;
        ti = q >> 4;
        tj = q & 15;
    }
    bi = BI * SP + ti;
    bj = BJ * SP + tj;
}

// ---------------------------------------------------------------------------
// d[i] = 1/sqrt(1 + sum_c part[c][i]); the +1 is the self-loop.
__global__ __launch_bounds__(256) void calc_d() {
    int i = blockIdx.x * blockDim.x + threadIdx.x;
    if (i < NMAT) {
        float s = 1.0f;
        #pragma unroll 8
        for (int c = 0; c < GT; ++c) s += g_part[c][i];
        g_dvec[i] = (s > 0.0f) ? (float)(1.0 / sqrt((double)s)) : 0.0f;
    }
}

// ---------------------------------------------------------------------------
// Pass 1: g_part[bj][bi*64+r] = sum over tile cols of max(A[i,j], A[j,i]),
// and (off-diag) g_part[bi][bj*64+q] for the mirrored rows. Plain stores —
// each slot written by exactly one block.
__global__ __launch_bounds__(256) void pass1_rowsum(const float* __restrict__ A) {
    __shared__ float Yl[64][65];
    __shared__ float colbuf[4][64];

    int bi, bj;
    decode_pair_sp((int)blockIdx.x, bi, bj);

    const int tid   = threadIdx.x;
    const int l16   = tid & 15;
    const int g16   = tid >> 4;
    const int cbase = l16 * 4;
    const int lane  = tid & 63;
    const int w     = tid >> 6;

    const float* Ybase = A + (size_t)(bj * 64) * NMAT + bi * 64;
    const float* Xbase = A + (size_t)(bi * 64) * NMAT + bj * 64;

    // Prefetch BOTH tiles into registers before any barrier (8 outstanding
    // 16B loads per thread — overlaps both tiles' HBM latency).
    f4 y[4], x[4];
    for (int k = 0; k < 4; ++k) {
        int q = k * 16 + g16;
        y[k] = *(const f4*)(Ybase + (size_t)q * NMAT + cbase);
    }
    for (int k = 0; k < 4; ++k) {
        int r = k * 16 + g16;
        x[k] = *(const f4*)(Xbase + (size_t)r * NMAT + cbase);
    }

    for (int k = 0; k < 4; ++k) {
        int q = k * 16 + g16;
        Yl[q][cbase + 0] = y[k].x;
        Yl[q][cbase + 1] = y[k].y;
        Yl[q][cbase + 2] = y[k].z;
        Yl[q][cbase + 3] = y[k].w;
    }
    __syncthreads();

    float cs0 = 0.f, cs1 = 0.f, cs2 = 0.f, cs3 = 0.f;

    for (int k = 0; k < 4; ++k) {
        int r = k * 16 + g16;
        float m0 = fmaxf(x[k].x, Yl[cbase + 0][r]);
        float m1 = fmaxf(x[k].y, Yl[cbase + 1][r]);
        float m2 = fmaxf(x[k].z, Yl[cbase + 2][r]);
        float m3 = fmaxf(x[k].w, Yl[cbase + 3][r]);
        cs0 += m0; cs1 += m1; cs2 += m2; cs3 += m3;
        float rt = (m0 + m1) + (m2 + m3);
        rt += __shfl_xor(rt, 1);
        rt += __shfl_xor(rt, 2);
        rt += __shfl_xor(rt, 4);
        rt += __shfl_xor(rt, 8);
        if (l16 == 0) g_part[bj][bi * 64 + r] = rt;   // unique slot, no atomic
    }

    if (bi != bj) {
        cs0 += __shfl_xor(cs0, 16); cs0 += __shfl_xor(cs0, 32);
        cs1 += __shfl_xor(cs1, 16); cs1 += __shfl_xor(cs1, 32);
        cs2 += __shfl_xor(cs2, 16); cs2 += __shfl_xor(cs2, 32);
        cs3 += __shfl_xor(cs3, 16); cs3 += __shfl_xor(cs3, 32);
        if (lane < 16) {
            colbuf[w][lane * 4 + 0] = cs0;
            colbuf[w][lane * 4 + 1] = cs1;
            colbuf[w][lane * 4 + 2] = cs2;
            colbuf[w][lane * 4 + 3] = cs3;
        }
        __syncthreads();
        if (tid < 64) {
            float t = (colbuf[0][tid] + colbuf[1][tid]) +
                      (colbuf[2][tid] + colbuf[3][tid]);
            g_part[bi][bj * 64 + tid] = t;            // unique slot, no atomic
        }
    }
}

// ---------------------------------------------------------------------------
// Pass 2: out[i,j] = d[i]*d[j]*(max(A[i,j],A[j,i]) + (i==j)).
// Block order REVERSED vs pass 1 so the tail of A (still resident in the
// 256 MiB Infinity Cache after pass 1) is re-read first -> LLC hits.
// Non-temporal stores keep the 268 MB of output writes from evicting A.
__global__ __launch_bounds__(256) void pass2_scale(const float* __restrict__ A,
                                                   float* __restrict__ out) {
    __shared__ float Yl[64][65];

    int bi, bj;
    decode_pair_sp(NPAIRS - 1 - (int)blockIdx.x, bi, bj);

    const int tid   = threadIdx.x;
    const int l16   = tid & 15;
    const int g16   = tid >> 4;
    const int cbase = l16 * 4;

    const float* Ybase = A + (size_t)(bj * 64) * NMAT + bi * 64;
    const float* Xbase = A + (size_t)(bi * 64) * NMAT + bj * 64;

    f4 y[4], x[4];
    for (int k = 0; k < 4; ++k) {
        int q = k * 16 + g16;
        y[k] = *(const f4*)(Ybase + (size_t)q * NMAT + cbase);
    }
    for (int k = 0; k < 4; ++k) {
        int r = k * 16 + g16;
        x[k] = *(const f4*)(Xbase + (size_t)r * NMAT + cbase);
    }

    for (int k = 0; k < 4; ++k) {
        int q = k * 16 + g16;
        Yl[q][cbase + 0] = y[k].x;
        Yl[q][cbase + 1] = y[k].y;
        Yl[q][cbase + 2] = y[k].z;
        Yl[q][cbase + 3] = y[k].w;
    }
    __syncthreads();

    const f4 dj = *(const f4*)(g_dvec + bj * 64 + cbase);
    const bool diag = (bi == bj);

    for (int k = 0; k < 4; ++k) {
        int r = k * 16 + g16;
        float di = g_dvec[bi * 64 + r];
        float m0 = fmaxf(x[k].x, Yl[cbase + 0][r]);
        float m1 = fmaxf(x[k].y, Yl[cbase + 1][r]);
        float m2 = fmaxf(x[k].z, Yl[cbase + 2][r]);
        float m3 = fmaxf(x[k].w, Yl[cbase + 3][r]);
        if (diag) {
            if (r == cbase + 0) m0 += 1.0f;
            if (r == cbase + 1) m1 += 1.0f;
            if (r == cbase + 2) m2 += 1.0f;
            if (r == cbase + 3) m3 += 1.0f;
        }
        f4 v;
        v.x = di * dj.x * m0;
        v.y = di * dj.y * m1;
        v.z = di * dj.z * m2;
        v.w = di * dj.w * m3;
        __builtin_nontemporal_store(v, (f4*)(out + (size_t)(bi * 64 + r) * NMAT + bj * 64 + cbase));
        // Stash scaled values (each LDS slot owned by exactly one thread).
        Yl[cbase + 0][r] = v.x;
        Yl[cbase + 1][r] = v.y;
        Yl[cbase + 2][r] = v.z;
        Yl[cbase + 3][r] = v.w;
    }

    if (!diag) {
        __syncthreads();
        for (int k = 0; k < 4; ++k) {
            int q = k * 16 + g16;
            f4 v;
            v.x = Yl[q][cbase + 0];
            v.y = Yl[q][cbase + 1];
            v.z = Yl[q][cbase + 2];
            v.w = Yl[q][cbase + 3];
            __builtin_nontemporal_store(v, (f4*)(out + (size_t)(bj * 64 + q) * NMAT + bi * 64 + cbase));
        }
    }
}

// ---------------------------------------------------------------------------
extern "C" void kernel_launch(void* const* d_in, const int* in_sizes, int n_in,
                              void* d_out, int out_size, void* d_ws, size_t ws_size,
                              hipStream_t stream) {
    const float* A = (const float*)d_in[0];
    float* out     = (float*)d_out;

    pass1_rowsum<<<NPAIRS, 256, 0, stream>>>(A);
    calc_d<<<NMAT / 256, 256, 0, stream>>>();
    pass2_scale<<<NPAIRS, 256, 0, stream>>>(A, out);
}

// Round 4
// 469.882 us; speedup vs baseline: 1.0442x; 1.0442x over previous
//
#include <hip/hip_runtime.h>
#include <math.h>

#define NMAT 8192
#define TS   128                    // tile edge (was 64): 512 B global chunks
#define GT   (NMAT / TS)            // 64 tiles per dim
#define NPAIRS (GT * (GT + 1) / 2)  // 2080

typedef float f4 __attribute__((ext_vector_type(4)));

// Module-scope scratch. g_part[c][i] = contribution of column-tile c to
// rowsum[i]; each slot written by exactly ONE block -> no init, no atomics.
__device__ __align__(16) float g_part[GT][NMAT];   // 2 MiB
__device__ __align__(16) float g_dvec[NMAT];

// ---------------------------------------------------------------------------
// Triangular pair decode: linear p -> (bi, bj), bi <= bj.
__device__ __forceinline__ int tri_off(int b) {
    return b * GT - ((b * (b - 1)) >> 1);
}

__device__ __forceinline__ void decode_pair(int p, int& bi, int& bj) {
    double dp = (double)p;
    double t = 2.0 * GT + 1.0;
    int b = (int)((t - sqrt(t * t - 8.0 * dp)) * 0.5);
    if (b < 0) b = 0;
    if (b > GT - 1) b = GT - 1;
    while (b + 1 < GT && tri_off(b + 1) <= p) ++b;
    while (b > 0 && tri_off(b) > p) --b;
    bi = b;
    bj = b + (p - tri_off(b));
}

// ---------------------------------------------------------------------------
// d[i] = 1/sqrt(1 + sum_c part[c][i]); the +1 is the self-loop.
__global__ __launch_bounds__(256) void calc_d() {
    int i = blockIdx.x * blockDim.x + threadIdx.x;
    if (i < NMAT) {
        float s = 1.0f;
        #pragma unroll 8
        for (int c = 0; c < GT; ++c) s += g_part[c][i];
        g_dvec[i] = (s > 0.0f) ? (float)(1.0 / sqrt((double)s)) : 0.0f;
    }
}

// ---------------------------------------------------------------------------
// LDS layout: Yl[row][col ^ ((row>>2)&31)], stride 128 words (no pad).
// Transposed compute read (col fixed per thread, row varying) lands on 32
// distinct banks -> conflict-free; staging writes are 4-way (cheap,
// overlapped with VMEM waits). [128][129] padding would instead make the
// transposed reads 4-way.
//
// Pass 1: g_part[bj][bi*TS+r] = row sums of max(A[i,j],A[j,i]) over the
// tile pair; off-diag also g_part[bi][bj*TS+c] for the mirrored columns.
// NOTE: no min-waves hint — pass1's 72 KB LDS caps occupancy at 2 blocks/CU
// already; forcing 64 VGPRs (the old (1024,8) bound) only risked spills.
__global__ __launch_bounds__(1024) void pass1_rowsum(const float* __restrict__ A) {
    __shared__ float Yl[TS][TS];        // 64 KB, XOR-swizzled
    __shared__ float colbuf[16][TS];    // 8 KB

    int bi, bj;
    decode_pair((int)blockIdx.x, bi, bj);

    const int tid   = threadIdx.x;
    const int l32   = tid & 31;
    const int g32   = tid >> 5;         // 0..31
    const int cbase = l32 * 4;
    const int w     = tid >> 6;         // wave 0..15
    const bool diag = (bi == bj);

    const float* Xbase = A + (size_t)(bi * TS) * NMAT + bj * TS;
    const float* Ybase = A + (size_t)(bj * TS) * NMAT + bi * TS;

    // Prefetch: 4 (or 8) outstanding 16B loads/thread, each wave-instruction
    // covering 2 rows x 512 B contiguous.
    f4 x[4], y[4];
    #pragma unroll
    for (int k = 0; k < 4; ++k)
        x[k] = *(const f4*)(Xbase + (size_t)(k * 32 + g32) * NMAT + cbase);
    if (!diag) {
        #pragma unroll
        for (int k = 0; k < 4; ++k)
            y[k] = *(const f4*)(Ybase + (size_t)(k * 32 + g32) * NMAT + cbase);
    }

    #pragma unroll
    for (int k = 0; k < 4; ++k) {
        int r = k * 32 + g32;
        f4 v = diag ? x[k] : y[k];      // diag: mirror tile == own tile
        int s = (r >> 2) & 31;
        Yl[r][(cbase + 0) ^ s] = v.x;
        Yl[r][(cbase + 1) ^ s] = v.y;
        Yl[r][(cbase + 2) ^ s] = v.z;
        Yl[r][(cbase + 3) ^ s] = v.w;
    }
    __syncthreads();

    float cs0 = 0.f, cs1 = 0.f, cs2 = 0.f, cs3 = 0.f;

    #pragma unroll
    for (int k = 0; k < 4; ++k) {
        int r  = k * 32 + g32;
        int rs = r ^ l32;               // swizzle of rows cbase..cbase+3 is l32
        float m0 = fmaxf(x[k].x, Yl[cbase + 0][rs]);
        float m1 = fmaxf(x[k].y, Yl[cbase + 1][rs]);
        float m2 = fmaxf(x[k].z, Yl[cbase + 2][rs]);
        float m3 = fmaxf(x[k].w, Yl[cbase + 3][rs]);
        cs0 += m0; cs1 += m1; cs2 += m2; cs3 += m3;
        float rt = (m0 + m1) + (m2 + m3);
        rt += __shfl_xor(rt, 1);
        rt += __shfl_xor(rt, 2);
        rt += __shfl_xor(rt, 4);
        rt += __shfl_xor(rt, 8);
        rt += __shfl_xor(rt, 16);       // row total across 32 lanes (half-wave)
        if (l32 == 0) g_part[bj][bi * TS + r] = rt;   // unique slot
    }

    if (!diag) {
        // Column sums: combine the wave's two row-groups, then across waves.
        cs0 += __shfl_xor(cs0, 32);
        cs1 += __shfl_xor(cs1, 32);
        cs2 += __shfl_xor(cs2, 32);
        cs3 += __shfl_xor(cs3, 32);
        if (!(tid & 32)) {
            colbuf[w][cbase + 0] = cs0;
            colbuf[w][cbase + 1] = cs1;
            colbuf[w][cbase + 2] = cs2;
            colbuf[w][cbase + 3] = cs3;
        }
        __syncthreads();
        if (tid < TS) {
            float t = 0.f;
            #pragma unroll
            for (int v = 0; v < 16; ++v) t += colbuf[v][tid];
            g_part[bi][bj * TS + tid] = t;            // unique slot
        }
    }
}

// ---------------------------------------------------------------------------
// Pass 2: out[i,j] = d[i]*d[j]*(max(A[i,j],A[j,i]) + (i==j)).
// Block order reversed vs pass 1 (L3-tail reuse); non-temporal stores.
__global__ __launch_bounds__(1024) void pass2_scale(const float* __restrict__ A,
                                                    float* __restrict__ out) {
    __shared__ float Yl[TS][TS];

    int bi, bj;
    decode_pair(NPAIRS - 1 - (int)blockIdx.x, bi, bj);

    const int tid   = threadIdx.x;
    const int l32   = tid & 31;
    const int g32   = tid >> 5;
    const int cbase = l32 * 4;
    const bool diag = (bi == bj);

    const float* Xbase = A + (size_t)(bi * TS) * NMAT + bj * TS;
    const float* Ybase = A + (size_t)(bj * TS) * NMAT + bi * TS;

    f4 x[4], y[4];
    #pragma unroll
    for (int k = 0; k < 4; ++k)
        x[k] = *(const f4*)(Xbase + (size_t)(k * 32 + g32) * NMAT + cbase);
    if (!diag) {
        #pragma unroll
        for (int k = 0; k < 4; ++k)
            y[k] = *(const f4*)(Ybase + (size_t)(k * 32 + g32) * NMAT + cbase);
    }

    #pragma unroll
    for (int k = 0; k < 4; ++k) {
        int r = k * 32 + g32;
        f4 v = diag ? x[k] : y[k];
        int s = (r >> 2) & 31;
        Yl[r][(cbase + 0) ^ s] = v.x;
        Yl[r][(cbase + 1) ^ s] = v.y;
        Yl[r][(cbase + 2) ^ s] = v.z;
        Yl[r][(cbase + 3) ^ s] = v.w;
    }
    __syncthreads();

    const f4 dj = *(const f4*)(g_dvec + bj * TS + cbase);

    #pragma unroll
    for (int k = 0; k < 4; ++k) {
        int r  = k * 32 + g32;
        int rs = r ^ l32;
        float di = g_dvec[bi * TS + r];
        float m0 = fmaxf(x[k].x, Yl[cbase + 0][rs]);
        float m1 = fmaxf(x[k].y, Yl[cbase + 1][rs]);
        float m2 = fmaxf(x[k].z, Yl[cbase + 2][rs]);
        float m3 = fmaxf(x[k].w, Yl[cbase + 3][rs]);
        if (diag) {
            if (r == cbase + 0) m0 += 1.0f;
            if (r == cbase + 1) m1 += 1.0f;
            if (r == cbase + 2) m2 += 1.0f;
            if (r == cbase + 3) m3 += 1.0f;
        }
        f4 v;
        v.x = di * dj.x * m0;
        v.y = di * dj.y * m1;
        v.z = di * dj.z * m2;
        v.w = di * dj.w * m3;
        __builtin_nontemporal_store(v, (f4*)(out + (size_t)(bi * TS + r) * NMAT + bj * TS + cbase));
        // Stash scaled values back into the slots this thread just read
        // (same thread, same address, and no other warp ever reads them).
        Yl[cbase + 0][rs] = v.x;
        Yl[cbase + 1][rs] = v.y;
        Yl[cbase + 2][rs] = v.z;
        Yl[cbase + 3][rs] = v.w;
    }

    if (!diag) {
        __syncthreads();
        #pragma unroll
        for (int k = 0; k < 4; ++k) {
            int q  = k * 32 + g32;
            int sq = (q >> 2) & 31;
            // stash[c][r] lives at Yl[c][r ^ ((c>>2)&31)]; mirror element
            // (row bj*TS+q, col bi*TS+t) = stash[q][t].
            f4 v;
            v.x = Yl[q][(cbase + 0) ^ sq];
            v.y = Yl[q][(cbase + 1) ^ sq];
            v.z = Yl[q][(cbase + 2) ^ sq];
            v.w = Yl[q][(cbase + 3) ^ sq];
            __builtin_nontemporal_store(v, (f4*)(out + (size_t)(bj * TS + q) * NMAT + bi * TS + cbase));
        }
    }
}

// ---------------------------------------------------------------------------
extern "C" void kernel_launch(void* const* d_in, const int* in_sizes, int n_in,
                              void* d_out, int out_size, void* d_ws, size_t ws_size,
                              hipStream_t stream) {
    const float* A = (const float*)d_in[0];
    float* out     = (float*)d_out;

    pass1_rowsum<<<NPAIRS, 1024, 0, stream>>>(A);
    calc_d<<<NMAT / 256, 256, 0, stream>>>();
    pass2_scale<<<NPAIRS, 1024, 0, stream>>>(A, out);
}